// Round 1
// baseline (20041.969 us; speedup 1.0000x reference)
//
#include <hip/hip_runtime.h>
#include <hip/hip_cooperative_groups.h>
#include <cstdint>
#include <cmath>

namespace cg = cooperative_groups;

// ---------------------------------------------------------------------------
// SelectiveWhElmanCell — round 1.
//  1) threefry RNG + 3-step power iteration -> scale (unchanged).
//  2) fused dual GEMM, retiled 128x128, 8x8 micro, dual accumulators:
//     xw = x@W_x^T + b -> out[t] slots; gate = sigmoid(x@W_gate^T) -> h[t+1].
//  3) ONE persistent cooperative kernel for all 256 steps: each of 256
//     blocks (1/CU) keeps 8 scaled rows of W_h in LDS (82 KB, forces
//     1 block/CU), computes Rh for its 8 columns, applies the elementwise
//     tail in-place, grid.sync() between steps.
// ---------------------------------------------------------------------------

static constexpr int Tt = 256;
static constexpr int Bb = 64;
static constexpr int Dk = 2048;
static constexpr int Mrows = Tt * Bb;          // 16384
static constexpr float EPSF = 1e-8f;
static constexpr float TARGET_RADIUS = 0.99f;

// ------------------------------ threefry -----------------------------------
__device__ __forceinline__ void tf_round(uint32_t& x0, uint32_t& x1, int r) {
    x0 += x1;
    x1 = (x1 << r) | (x1 >> (32 - r));
    x1 ^= x0;
}

__device__ __forceinline__ uint2 threefry2x32(uint32_t ks0, uint32_t ks1,
                                              uint32_t x0, uint32_t x1) {
    uint32_t ks2 = ks0 ^ ks1 ^ 0x1BD11BDAu;
    x0 += ks0; x1 += ks1;
    tf_round(x0,x1,13); tf_round(x0,x1,15); tf_round(x0,x1,26); tf_round(x0,x1,6);
    x0 += ks1; x1 += ks2 + 1u;
    tf_round(x0,x1,17); tf_round(x0,x1,29); tf_round(x0,x1,16); tf_round(x0,x1,24);
    x0 += ks2; x1 += ks0 + 2u;
    tf_round(x0,x1,13); tf_round(x0,x1,15); tf_round(x0,x1,26); tf_round(x0,x1,6);
    x0 += ks0; x1 += ks1 + 3u;
    tf_round(x0,x1,17); tf_round(x0,x1,29); tf_round(x0,x1,16); tf_round(x0,x1,24);
    x0 += ks1; x1 += ks2 + 4u;
    tf_round(x0,x1,13); tf_round(x0,x1,15); tf_round(x0,x1,26); tf_round(x0,x1,6);
    x0 += ks2; x1 += ks0 + 5u;
    return make_uint2(x0, x1);
}

// u0 = normal(key(42), (2048,)); u0 /= ||u0||  (no eps on first normalize).
__global__ __launch_bounds__(256) void k_rng(float* __restrict__ u) {
    __shared__ float red[256];
    __shared__ float s_inv;
    float local = 0.f;
    for (int i = threadIdx.x; i < Dk; i += 256) {
        uint2 r = threefry2x32(0u, 42u, 0u, (uint32_t)i);
        uint32_t bits = r.x ^ r.y;
        uint32_t fb = (bits >> 9) | 0x3f800000u;
        float f01 = __uint_as_float(fb) - 1.0f;           // [0,1)
        const float lo = -0.99999994f;                    // nextafter(-1,0)
        float uu = f01 * (1.0f - lo) + lo;
        uu = fmaxf(lo, uu);
        float g = 1.41421356237f * erfinvf(uu);
        u[i] = g;
        local += g * g;
    }
    red[threadIdx.x] = local;
    __syncthreads();
    for (int s = 128; s > 0; s >>= 1) {
        if (threadIdx.x < s) red[threadIdx.x] += red[threadIdx.x + s];
        __syncthreads();
    }
    if (threadIdx.x == 0) s_inv = 1.0f / sqrtf(red[0]);
    __syncthreads();
    float inv = s_inv;
    for (int i = threadIdx.x; i < Dk; i += 256) u[i] *= inv;
}

// out[j] = sum_i W[i,j] * u[i]   (W^T @ u)
__global__ __launch_bounds__(256) void k_matvec_T(const float* __restrict__ W,
                                                  const float* __restrict__ u,
                                                  float* __restrict__ out) {
    __shared__ float us[Dk];
    for (int i = threadIdx.x; i < Dk; i += 256) us[i] = u[i];
    __syncthreads();
    int j = blockIdx.x * 256 + threadIdx.x;
    float acc = 0.f;
    for (int i = 0; i < Dk; ++i) acc += W[(size_t)i * Dk + j] * us[i];
    out[j] = acc;
}

// out[row] = sum_j W[row,j] * v[j]   (W @ v), one block per row
__global__ __launch_bounds__(256) void k_matvec_N(const float* __restrict__ W,
                                                  const float* __restrict__ v,
                                                  float* __restrict__ out) {
    __shared__ float red[256];
    const float* Wr = W + (size_t)blockIdx.x * Dk;
    float acc = 0.f;
    for (int j = threadIdx.x; j < Dk; j += 256) acc += Wr[j] * v[j];
    red[threadIdx.x] = acc;
    __syncthreads();
    for (int s = 128; s > 0; s >>= 1) {
        if (threadIdx.x < s) red[threadIdx.x] += red[threadIdx.x + s];
        __syncthreads();
    }
    if (threadIdx.x == 0) out[blockIdx.x] = red[0];
}

// vec /= (||vec|| + eps)
__global__ __launch_bounds__(256) void k_normalize(float* __restrict__ vec) {
    __shared__ float red[256];
    __shared__ float s_inv;
    float acc = 0.f;
    for (int i = threadIdx.x; i < Dk; i += 256) { float x = vec[i]; acc += x * x; }
    red[threadIdx.x] = acc;
    __syncthreads();
    for (int s = 128; s > 0; s >>= 1) {
        if (threadIdx.x < s) red[threadIdx.x] += red[threadIdx.x + s];
        __syncthreads();
    }
    if (threadIdx.x == 0) s_inv = 1.0f / (sqrtf(red[0]) + EPSF);
    __syncthreads();
    float inv = s_inv;
    for (int i = threadIdx.x; i < Dk; i += 256) vec[i] *= inv;
}

// sigma = ||uraw||^2/(||uraw||+eps); scale = 0.99/(sigma+eps)
__global__ __launch_bounds__(256) void k_sigma(const float* __restrict__ uraw,
                                               float* __restrict__ scale_out) {
    __shared__ float red[256];
    float acc = 0.f;
    for (int i = threadIdx.x; i < Dk; i += 256) { float x = uraw[i]; acc += x * x; }
    red[threadIdx.x] = acc;
    __syncthreads();
    for (int s = 128; s > 0; s >>= 1) {
        if (threadIdx.x < s) red[threadIdx.x] += red[threadIdx.x + s];
        __syncthreads();
    }
    if (threadIdx.x == 0) {
        float ss = red[0];
        float n = sqrtf(ss);
        float sigma = ss / (n + EPSF);
        scale_out[0] = TARGET_RADIUS / (sigma + EPSF);
    }
}

// --------------------------- fused dual GEMM -------------------------------
// xw[m,n]   = sum_k X[m,k]*Wx[n,k] + bias[n]
// gate[m,n] = sigmoid(sum_k X[m,k]*Wg[n,k])
// BM=BN=128, BK=16, 256 threads, 8x8 micro-tile, dual accumulators.
__global__ __launch_bounds__(256, 2) void k_dualgemm(const float* __restrict__ X,
                                                     const float* __restrict__ Wx,
                                                     const float* __restrict__ Wg,
                                                     const float* __restrict__ bias,
                                                     float* __restrict__ xw_out,
                                                     float* __restrict__ gate_out) {
    __shared__ float As [16][132];   // [k][m], pad keeps float4 align, 2-way max
    __shared__ float Bxs[16][132];   // [k][n]
    __shared__ float Bgs[16][132];

    const int tid = threadIdx.x;
    const int bm = blockIdx.x;   // 0..127
    const int bn = blockIdx.y;   // 0..15
    const int tx = tid & 15;     // n-group (8 cols each)
    const int ty = tid >> 4;     // m-group (8 rows each)

    float accX[8][8] = {};
    float accG[8][8] = {};

    const int lrow = tid >> 2;        // 0..63
    const int lk4  = (tid & 3) << 2;  // 0,4,8,12
    const float* Xp0  = X  + (size_t)(bm * 128 + lrow) * Dk + lk4;
    const float* Xp1  = Xp0 + (size_t)64 * Dk;
    const float* Wxp0 = Wx + (size_t)(bn * 128 + lrow) * Dk + lk4;
    const float* Wxp1 = Wxp0 + (size_t)64 * Dk;
    const float* Wgp0 = Wg + (size_t)(bn * 128 + lrow) * Dk + lk4;
    const float* Wgp1 = Wgp0 + (size_t)64 * Dk;

    for (int k0 = 0; k0 < Dk; k0 += 16) {
        float4 xa0 = *(const float4*)(Xp0  + k0);
        float4 xa1 = *(const float4*)(Xp1  + k0);
        float4 wx0 = *(const float4*)(Wxp0 + k0);
        float4 wx1 = *(const float4*)(Wxp1 + k0);
        float4 wg0 = *(const float4*)(Wgp0 + k0);
        float4 wg1 = *(const float4*)(Wgp1 + k0);
        __syncthreads();
        As [lk4 + 0][lrow]      = xa0.x; As [lk4 + 1][lrow]      = xa0.y;
        As [lk4 + 2][lrow]      = xa0.z; As [lk4 + 3][lrow]      = xa0.w;
        As [lk4 + 0][lrow + 64] = xa1.x; As [lk4 + 1][lrow + 64] = xa1.y;
        As [lk4 + 2][lrow + 64] = xa1.z; As [lk4 + 3][lrow + 64] = xa1.w;
        Bxs[lk4 + 0][lrow]      = wx0.x; Bxs[lk4 + 1][lrow]      = wx0.y;
        Bxs[lk4 + 2][lrow]      = wx0.z; Bxs[lk4 + 3][lrow]      = wx0.w;
        Bxs[lk4 + 0][lrow + 64] = wx1.x; Bxs[lk4 + 1][lrow + 64] = wx1.y;
        Bxs[lk4 + 2][lrow + 64] = wx1.z; Bxs[lk4 + 3][lrow + 64] = wx1.w;
        Bgs[lk4 + 0][lrow]      = wg0.x; Bgs[lk4 + 1][lrow]      = wg0.y;
        Bgs[lk4 + 2][lrow]      = wg0.z; Bgs[lk4 + 3][lrow]      = wg0.w;
        Bgs[lk4 + 0][lrow + 64] = wg1.x; Bgs[lk4 + 1][lrow + 64] = wg1.y;
        Bgs[lk4 + 2][lrow + 64] = wg1.z; Bgs[lk4 + 3][lrow + 64] = wg1.w;
        __syncthreads();
#pragma unroll
        for (int kk = 0; kk < 16; ++kk) {
            const float4 a0 = *(const float4*)&As [kk][ty * 8];
            const float4 a1 = *(const float4*)&As [kk][ty * 8 + 4];
            const float4 x0 = *(const float4*)&Bxs[kk][tx * 8];
            const float4 x1 = *(const float4*)&Bxs[kk][tx * 8 + 4];
            const float4 g0 = *(const float4*)&Bgs[kk][tx * 8];
            const float4 g1 = *(const float4*)&Bgs[kk][tx * 8 + 4];
            float av[8] = {a0.x, a0.y, a0.z, a0.w, a1.x, a1.y, a1.z, a1.w};
            float xv[8] = {x0.x, x0.y, x0.z, x0.w, x1.x, x1.y, x1.z, x1.w};
            float gv[8] = {g0.x, g0.y, g0.z, g0.w, g1.x, g1.y, g1.z, g1.w};
#pragma unroll
            for (int i = 0; i < 8; ++i)
#pragma unroll
                for (int j = 0; j < 8; ++j) {
                    accX[i][j] = fmaf(av[i], xv[j], accX[i][j]);
                    accG[i][j] = fmaf(av[i], gv[j], accG[i][j]);
                }
        }
    }

    const int m0 = bm * 128 + ty * 8;
    const int n0 = bn * 128 + tx * 8;
    float4 bv0 = *(const float4*)(bias + n0);
    float4 bv1 = *(const float4*)(bias + n0 + 4);
#pragma unroll
    for (int i = 0; i < 8; ++i) {
        float4 xo0, xo1, go0, go1;
        xo0.x = accX[i][0] + bv0.x; xo0.y = accX[i][1] + bv0.y;
        xo0.z = accX[i][2] + bv0.z; xo0.w = accX[i][3] + bv0.w;
        xo1.x = accX[i][4] + bv1.x; xo1.y = accX[i][5] + bv1.y;
        xo1.z = accX[i][6] + bv1.z; xo1.w = accX[i][7] + bv1.w;
        go0.x = 1.0f / (1.0f + expf(-accG[i][0]));
        go0.y = 1.0f / (1.0f + expf(-accG[i][1]));
        go0.z = 1.0f / (1.0f + expf(-accG[i][2]));
        go0.w = 1.0f / (1.0f + expf(-accG[i][3]));
        go1.x = 1.0f / (1.0f + expf(-accG[i][4]));
        go1.y = 1.0f / (1.0f + expf(-accG[i][5]));
        go1.z = 1.0f / (1.0f + expf(-accG[i][6]));
        go1.w = 1.0f / (1.0f + expf(-accG[i][7]));
        float* xrow = xw_out   + (size_t)(m0 + i) * Dk + n0;
        float* grow = gate_out + (size_t)(m0 + i) * Dk + n0;
        *(float4*)xrow       = xo0;
        *(float4*)(xrow + 4) = xo1;
        *(float4*)grow       = go0;
        *(float4*)(grow + 4) = go1;
    }
}

// --------------------- persistent cooperative recurrence -------------------
// 256 blocks (1/CU, enforced by 82 KB LDS) x 256 threads. Block b owns
// columns e0 = 8*b .. 8*b+7: its 8 rows of W_h (pre-scaled) live in LDS for
// the whole sequence. Thread t: e = t&7, rows (t>>3) and (t>>3)+32.
// Per step: Rh[b,e] = sum_d h[t][b,d]*Ws[e][d]; h_new = tanh(xw + Rh*gate);
// out = h_new*silu(z). xw lives at out[t] (overwritten with out), gate lives
// at h[t+1] (overwritten with h_new). grid.sync() between steps.
//
// LDS row stride 2564: (e*2564+d)%32 = 4e+d -> the 8 distinct w-addresses of
// a wave tile all 32 banks (conflict-free), and 8 lanes broadcast each one.
__global__ __launch_bounds__(256) void k_recur(const float* __restrict__ Wh,
                                               const float* __restrict__ scale_p,
                                               const float* __restrict__ z,
                                               float* __restrict__ out,
                                               float* __restrict__ hbuf) {
    cg::grid_group grid = cg::this_grid();
    __shared__ float Ws[8][2564];     // 82 KB -> exactly 1 block/CU

    const int tid = threadIdx.x;
    const int e0 = blockIdx.x * 8;
    const float sc = scale_p[0];

    // One-time: stage + scale this block's 8 rows of W_h.
    for (int idx = tid; idx < 8 * 512; idx += 256) {
        const int r = idx >> 9;
        const int c = (idx & 511) << 2;
        float4 w = *(const float4*)(Wh + (size_t)(e0 + r) * Dk + c);
        Ws[r][c + 0] = w.x * sc; Ws[r][c + 1] = w.y * sc;
        Ws[r][c + 2] = w.z * sc; Ws[r][c + 3] = w.w * sc;
    }
    __syncthreads();

    const int e = tid & 7;
    const int brow = tid >> 3;            // 0..31
    const float* wr = &Ws[e][0];
    const size_t BD = (size_t)Bb * Dk;
    const size_t i0 = (size_t)brow * Dk + e0 + e;
    const size_t i1 = i0 + (size_t)32 * Dk;

    for (int t = 0; t < Tt; ++t) {
        const float* hbase = hbuf + (size_t)t * BD;
        float* hg = hbuf + (size_t)(t + 1) * BD;   // gate in, h_new out
        float* xo = out  + (size_t)t * BD;         // xw in, out_t out
        const float* zt = z + (size_t)t * BD;

        // Issue elementwise operand loads early (all written before this
        // kernel or by this thread itself) — hidden under the dot loop.
        float g0 = hg[i0], g1 = hg[i1];
        float x0 = xo[i0], x1 = xo[i1];
        float z0 = zt[i0], z1 = zt[i1];

        const float* hp0 = hbase + (size_t)brow * Dk;
        const float* hp1 = hp0 + (size_t)32 * Dk;
        float s00 = 0.f, s01 = 0.f, s10 = 0.f, s11 = 0.f;
#pragma unroll 4
        for (int d = 0; d < Dk; d += 8) {
            float4 w0 = *(const float4*)(wr + d);
            float4 w1 = *(const float4*)(wr + d + 4);
            float4 a0 = *(const float4*)(hp0 + d);
            float4 a1 = *(const float4*)(hp0 + d + 4);
            float4 b0 = *(const float4*)(hp1 + d);
            float4 b1 = *(const float4*)(hp1 + d + 4);
            s00 = fmaf(a0.w, w0.w, fmaf(a0.z, w0.z, fmaf(a0.y, w0.y, fmaf(a0.x, w0.x, s00))));
            s01 = fmaf(a1.w, w1.w, fmaf(a1.z, w1.z, fmaf(a1.y, w1.y, fmaf(a1.x, w1.x, s01))));
            s10 = fmaf(b0.w, w0.w, fmaf(b0.z, w0.z, fmaf(b0.y, w0.y, fmaf(b0.x, w0.x, s10))));
            s11 = fmaf(b1.w, w1.w, fmaf(b1.z, w1.z, fmaf(b1.y, w1.y, fmaf(b1.x, w1.x, s11))));
        }
        float r0 = s00 + s01;
        float r1 = s10 + s11;

        float hn0 = tanhf(x0 + r0 * g0);
        float hn1 = tanhf(x1 + r1 * g1);
        float sz0 = z0 / (1.0f + expf(-z0));
        float sz1 = z1 / (1.0f + expf(-z1));
        hg[i0] = hn0; xo[i0] = hn0 * sz0;
        hg[i1] = hn1; xo[i1] = hn1 * sz1;

        if (t + 1 < Tt) grid.sync();
    }
}

// ------------------------------- launch ------------------------------------
extern "C" void kernel_launch(void* const* d_in, const int* in_sizes, int n_in,
                              void* d_out, int out_size, void* d_ws, size_t ws_size,
                              hipStream_t stream) {
    const float* x    = (const float*)d_in[0];
    const float* z    = (const float*)d_in[1];
    const float* h0   = (const float*)d_in[2];
    const float* Wx   = (const float*)d_in[3];
    const float* Wh   = (const float*)d_in[4];
    const float* Wg   = (const float*)d_in[5];
    const float* bias = (const float*)d_in[6];

    float* out  = (float*)d_out;                      // [T,B,D]
    float* hbuf = out + (size_t)Tt * Bb * Dk;         // [T+1,B,D]

    float* ws    = (float*)d_ws;
    float* u     = ws;          // 2048
    float* v     = ws + 2048;   // 2048
    float* tmp   = ws + 4096;   // 2048
    float* scale = ws + 6144;   // 1

    const size_t BD = (size_t)Bb * Dk;

    // h[0] = h0
    hipMemcpyAsync(hbuf, h0, BD * sizeof(float), hipMemcpyDeviceToDevice, stream);

    // spectral norm scale
    k_rng<<<1, 256, 0, stream>>>(u);
    float* uc = u;
    float* ut = tmp;
    for (int it = 0; it < 3; ++it) {
        k_matvec_T<<<8, 256, 0, stream>>>(Wh, uc, v);
        k_normalize<<<1, 256, 0, stream>>>(v);
        k_matvec_N<<<2048, 256, 0, stream>>>(Wh, v, ut);
        if (it < 2) {
            k_normalize<<<1, 256, 0, stream>>>(ut);
            float* t2 = uc; uc = ut; ut = t2;
        }
    }
    k_sigma<<<1, 256, 0, stream>>>(ut, scale);

    // fused input projections: xw -> out[t] slots, gate -> h[t+1] slots
    dim3 gg(Mrows / 128, Dk / 128);
    k_dualgemm<<<gg, 256, 0, stream>>>(x, Wx, Wg, bias, out, hbuf + BD);

    // persistent cooperative recurrence (all 256 steps in one launch)
    {
        const float* aWh = Wh;
        const float* aSc = scale;
        const float* aZ  = z;
        float* aOut = out;
        float* aH   = hbuf;
        void* kargs[] = {(void*)&aWh, (void*)&aSc, (void*)&aZ,
                         (void*)&aOut, (void*)&aH};
        hipLaunchCooperativeKernel(k_recur, dim3(256), dim3(256), kargs, 0, stream);
    }
}